// Round 6
// baseline (194.260 us; speedup 1.0000x reference)
//
#include <hip/hip_runtime.h>

typedef __attribute__((ext_vector_type(8))) short short8;
typedef __attribute__((ext_vector_type(4))) float floatx4;

// Problem constants
#define NEXP   36          // 12 tempers * 3 ops
#define NTOK   1024        // 128 batch * 8 patches
#define HOPS   4

// Workspace layout (bytes)
#define OFF_STATE   0u          // 1024*256*4      = 1,048,576
#define OFF_W1B     1048576u    // 36*65536*2      = 4,718,592 (bf16, swizzled)
#define OFF_W2B     5767168u    // 36*65536*2      = 4,718,592
#define OFF_C1      10485760u   // 36*256*4        = 36,864
#define OFF_COUNTS  10522624u   // 4*36*4          = 576
#define OFF_LISTS   10523264u   // 4*36*1024*4     = 589,824
#define OFF_JOBS    11113088u   // 4*128*4         = 2,048
#define OFF_NJ      11115136u   // 4*4             = 16
#define OFF_PROG    11115152u   // 1024*4          = 4,096  (end ~11.12 MB)

__device__ __forceinline__ unsigned short f2bf(float f) {
    unsigned u = __float_as_uint(f);
    u += 0x7FFFu + ((u >> 16) & 1u);   // round-to-nearest-even
    return (unsigned short)(u >> 16);
}

// ---------------------------------------------------------------------------
// PREP: one kernel, block-role partitioned.
//  blocks [0,2304)    : convert W1(first 256 rows)/W2 -> bf16 in B-frag layout
//                       Wb[e][kb][j][k32],  kb=k/32, k32=k%32
//  blocks [2304,2340) : c1[e][j] = b1[e][j] + sum_k emb[e][k]*W1[e][256+k][j]
//  blocks [2340,2404) : copy x -> state (f32)
//  block  2404        : routing (packed with dependency version) + jobs + prog
// ---------------------------------------------------------------------------
__global__ __launch_bounds__(256) void prep_kernel(
    const float* __restrict__ x, const float* __restrict__ W1,
    const float* __restrict__ b1, const float* __restrict__ W2,
    const float* __restrict__ op_emb,
    const int* __restrict__ tempers, const int* __restrict__ ops,
    float* __restrict__ state, unsigned short* __restrict__ W1b,
    unsigned short* __restrict__ W2b, float* __restrict__ c1,
    int* __restrict__ counts, int* __restrict__ lists,
    int* __restrict__ jobs, int* __restrict__ njobs, int* __restrict__ prog)
{
    const int bid = blockIdx.x;
    const int t = threadIdx.x;

    if (bid < 2304) {
        // ---- weight convert + swizzle ----
        const int mat = bid / 1152;           // 0: W1, 1: W2
        const int id  = bid % 1152;           // 36 experts * 8 kb * 4 jt
        const int e   = id / 32;
        const int sub = id % 32;
        const int kb  = sub / 4;
        const int jt  = sub % 4;
        const float* src = mat ? (W2 + e * 65536) : (W1 + e * 98304);
        unsigned short* dst = (mat ? W2b : W1b) + e * 65536;
        const int j  = jt * 64 + (t & 63);
        const int ks = (t >> 6) * 8;          // 8 consecutive k per thread
        short8 v;
        #pragma unroll
        for (int i = 0; i < 8; i++)
            v[i] = (short)f2bf(src[(kb * 32 + ks + i) * 256 + j]);  // coalesced across j
        *(short8*)(dst + (kb * 256 + j) * 32 + ks) = v;
    } else if (bid < 2340) {
        // ---- c1 precompute (fp32) ----
        const int e = bid - 2304;
        __shared__ float eb[128];
        if (t < 128) eb[t] = op_emb[e * 128 + t];
        __syncthreads();
        float acc = b1[e * 256 + t];
        const float* wp = W1 + e * 98304 + 256 * 256;  // emb rows of W1[e]
        #pragma unroll 4
        for (int k = 0; k < 128; k++)
            acc += eb[k] * wp[k * 256 + t];
        c1[e * 256 + t] = acc;
    } else if (bid < 2404) {
        // ---- state = x (f32 copy) ----
        const int cb = bid - 2340;
        const float4* xs = (const float4*)x;
        float4* ss = (float4*)state;
        #pragma unroll
        for (int p = 0; p < 4; p++) {
            int i4 = cb * 1024 + p * 256 + t;
            ss[i4] = xs[i4];
        }
    } else {
        // ---- routing (single block; cumulative-halt semantics) ----
        // list entry = n | (need<<12) where need = version (prev active hop+1)
        __shared__ int lc[HOPS * NEXP];
        if (t < HOPS * NEXP) lc[t] = 0;
        __syncthreads();
        for (int q = 0; q < 4; q++) {
            int n = q * 256 + t;
            prog[n] = 0;                       // token progress flags
            bool act = true;
            int la = 0;                        // version after last active hop
            for (int hop = 0; hop < HOPS; hop++) {
                int tt = tempers[hop * NTOK + n];
                int oo = ops[hop * NTOK + n];
                act = act && (tt != 12);       // 12 == halt; sticky
                if (act) {
                    int e = tt * 3 + oo;
                    int pos = atomicAdd(&lc[hop * NEXP + e], 1);
                    lists[(hop * NEXP + e) * NTOK + pos] = n | (la << 12);
                    la = hop + 1;
                }
            }
        }
        __syncthreads();
        if (t < HOPS * NEXP) counts[t] = lc[t];
        // ---- job compaction: one thread per hop; job = (m0<<8)|e ----
        if (t < HOPS) {
            int hop = t, nj = 0;
            for (int e = 0; e < NEXP; e++) {
                int c = lc[hop * NEXP + e];
                for (int m0 = 0; m0 < c; m0 += 16)
                    jobs[hop * 128 + nj++] = (m0 << 8) | e;
            }
            njobs[hop] = nj;
        }
    }
}

// ---------------------------------------------------------------------------
// HOPS (fused, dependency-pipelined): grid 256 = 4 hops x 64 slots, 1024 thr.
// Block (hop, slot) serially handles jobs slot, slot+64 of that hop (njobs
// <= 100). Instead of a grid barrier between hops, each token carries a
// version flag prog[n]; a job spins (16 lanes, agent scope) until its tokens
// reach the packed `need` version, computes the fused 2-GEMM, then
// release-publishes prog[n]=hop+1. 1024-thr blocks => VGPR<=128 => 1
// block/CU => all 256 blocks co-resident => deadlock-free (DAG by hop).
// MFMA maps (m89): A[m=l&15][k=(l>>4)*8+i]; D col=l&15, row=(l>>4)*4+reg.
// ---------------------------------------------------------------------------
__global__ __launch_bounds__(1024) void hops_kernel(
    float* __restrict__ state,
    const unsigned short* __restrict__ W1b,
    const unsigned short* __restrict__ W2b,
    const float* __restrict__ c1, const float* __restrict__ b2,
    const int* __restrict__ counts, const int* __restrict__ lists,
    const int* __restrict__ jobs, const int* __restrict__ njobs,
    int* __restrict__ prog)
{
    const int hop  = blockIdx.x >> 6;
    const int slot = blockIdx.x & 63;
    const int nj   = njobs[hop];

    const int t = threadIdx.x;
    const int l = t & 63, w = t >> 6;      // wave 0..15
    const int col = l & 15, g = l >> 4;
    const int j = w * 16 + col;            // this wave's output column

    __shared__ int tv[16];                 // packed token|need
    __shared__ unsigned short Ab[4096];    // [kb][lane][8] bf16, 8 KB
    __shared__ unsigned short Hb[4096];    // 8 KB

    for (int jb = slot; jb < nj; jb += 64) {
        const int job = jobs[hop * 128 + jb];
        const int e   = job & 0xFF;
        const int m0  = job >> 8;
        const int n_e = counts[hop * NEXP + e];
        const int mact = min(16, n_e - m0);

        // ---- preload B-frags + biases (independent of token wait) ----
        const unsigned short* Wp  = W1b + e * 65536;
        const unsigned short* Wp2 = W2b + e * 65536;
        short8 B1[8], B2[8];
        #pragma unroll
        for (int kb = 0; kb < 8; kb++) {
            B1[kb] = *(const short8*)(Wp  + (kb * 256 + j) * 32 + g * 8);
            B2[kb] = *(const short8*)(Wp2 + (kb * 256 + j) * 32 + g * 8);
        }
        const float cv = c1[e * 256 + j];
        const float bv = b2[e * 256 + j];

        __syncthreads();                   // LDS reuse guard across jobs
        if (t < 16) {
            int v = (t < mact) ? lists[(hop * NEXP + e) * NTOK + m0 + t] : 0;
            tv[t] = v;
            if (t < mact) {
                int n = v & 0xFFF, need = v >> 12;
                while (__hip_atomic_load(&prog[n], __ATOMIC_ACQUIRE,
                                         __HIP_MEMORY_SCOPE_AGENT) < need)
                    __builtin_amdgcn_s_sleep(1);
            }
        }
        __syncthreads();

        // ---- stage A tile: state rows (f32) -> bf16 in A-frag layout ----
        {
            int m = t >> 6;                // token row 0..15 (one wave per row)
            int k = (t & 63) * 4;          // float4 column
            float4 v = make_float4(0.f, 0.f, 0.f, 0.f);
            if (m < mact) v = *(const float4*)(state + (tv[m] & 0xFFF) * 256 + k);
            int kb = k >> 5, gg = (k >> 3) & 3, i = k & 7;
            unsigned short* d = Ab + kb * 512 + (gg * 16 + m) * 8 + i;
            d[0] = f2bf(v.x); d[1] = f2bf(v.y); d[2] = f2bf(v.z); d[3] = f2bf(v.w);
        }
        __syncthreads();

        // ---- GEMM1 (weights in registers) ----
        floatx4 acc = (floatx4){cv, cv, cv, cv};
        #pragma unroll
        for (int kb = 0; kb < 8; kb++) {
            short8 a = *(const short8*)(Ab + kb * 512 + l * 8);
            acc = __builtin_amdgcn_mfma_f32_16x16x32_bf16(a, B1[kb], acc, 0, 0, 0);
        }
        // ---- epilogue 1: relu -> Hb in A-frag layout (h-dim becomes K) ----
        {
            int kb2 = j >> 5, g2 = (j >> 3) & 3, i2 = j & 7;
            #pragma unroll
            for (int r = 0; r < 4; r++) {
                int m = g * 4 + r;         // D row (token)
                float vv = acc[r];
                vv = vv > 0.f ? vv : 0.f;
                Hb[kb2 * 512 + (g2 * 16 + m) * 8 + i2] = f2bf(vv);
            }
        }
        __syncthreads();

        // ---- GEMM2 ----
        floatx4 acc2 = (floatx4){bv, bv, bv, bv};
        #pragma unroll
        for (int kb = 0; kb < 8; kb++) {
            short8 a = *(const short8*)(Hb + kb * 512 + l * 8);
            acc2 = __builtin_amdgcn_mfma_f32_16x16x32_bf16(a, B2[kb], acc2, 0, 0, 0);
        }
        // ---- epilogue 2: relu -> state (f32), only real rows ----
        #pragma unroll
        for (int r = 0; r < 4; r++) {
            int m = g * 4 + r;
            if (m < mact) {
                float vv = acc2[r];
                state[(tv[m] & 0xFFF) * 256 + j] = vv > 0.f ? vv : 0.f;
            }
        }

        // ---- publish: all block stores done -> release token versions ----
        __syncthreads();                   // drains vmcnt before barrier
        if (t < mact) {                    // t < 16
            __threadfence();
            __hip_atomic_store(&prog[tv[t] & 0xFFF], hop + 1,
                               __ATOMIC_RELEASE, __HIP_MEMORY_SCOPE_AGENT);
        }
    }
}

// ---------------------------------------------------------------------------
// FINAL: mean-pool 8 patches -> LayerNorm -> 10-class head. One block/batch.
// ---------------------------------------------------------------------------
__global__ __launch_bounds__(256) void final_kernel(
    const float* __restrict__ state, const float* __restrict__ ln_g,
    const float* __restrict__ ln_b, const float* __restrict__ Wt,
    const float* __restrict__ bt, float* __restrict__ out)
{
    const int b = blockIdx.x, t = threadIdx.x;
    float s = 0.f;
    #pragma unroll
    for (int p = 0; p < 8; p++) s += state[(b * 8 + p) * 256 + t];
    s *= 0.125f;

    float v1 = s, v2 = s * s;
    #pragma unroll
    for (int off = 32; off; off >>= 1) {
        v1 += __shfl_down(v1, off);
        v2 += __shfl_down(v2, off);
    }
    __shared__ float red[8];
    __shared__ float stats[2];
    const int w = t >> 6, l = t & 63;
    if (l == 0) { red[w] = v1; red[4 + w] = v2; }
    __syncthreads();
    if (t == 0) {
        float su = red[0] + red[1] + red[2] + red[3];
        float sq = red[4] + red[5] + red[6] + red[7];
        float mu = su * (1.0f / 256.0f);
        float var = sq * (1.0f / 256.0f) - mu * mu;
        stats[0] = mu;
        stats[1] = rsqrtf(var + 1e-5f);
    }
    __syncthreads();
    float normed = (s - stats[0]) * stats[1] * ln_g[t] + ln_b[t];

    __shared__ float pr[40];
    #pragma unroll
    for (int c = 0; c < 10; c++) {
        float pv = normed * Wt[t * 10 + c];
        #pragma unroll
        for (int off = 32; off; off >>= 1) pv += __shfl_down(pv, off);
        if (l == 0) pr[w * 10 + c] = pv;
    }
    __syncthreads();
    if (t < 10)
        out[b * 10 + t] = pr[t] + pr[10 + t] + pr[20 + t] + pr[30 + t] + bt[t];
}

extern "C" void kernel_launch(void* const* d_in, const int* in_sizes, int n_in,
                              void* d_out, int out_size, void* d_ws, size_t ws_size,
                              hipStream_t stream)
{
    const float* x      = (const float*)d_in[0];
    const float* W1     = (const float*)d_in[1];
    const float* b1     = (const float*)d_in[2];
    const float* W2     = (const float*)d_in[3];
    const float* b2     = (const float*)d_in[4];
    const float* op_emb = (const float*)d_in[5];
    const float* ln_g   = (const float*)d_in[6];
    const float* ln_b   = (const float*)d_in[7];
    const float* Wt     = (const float*)d_in[8];
    const float* bt     = (const float*)d_in[9];
    const int* tempers  = (const int*)d_in[10];
    const int* ops      = (const int*)d_in[11];

    char* ws = (char*)d_ws;
    float* state          = (float*)(ws + OFF_STATE);
    unsigned short* W1b   = (unsigned short*)(ws + OFF_W1B);
    unsigned short* W2b   = (unsigned short*)(ws + OFF_W2B);
    float* c1             = (float*)(ws + OFF_C1);
    int* counts           = (int*)(ws + OFF_COUNTS);
    int* lists            = (int*)(ws + OFF_LISTS);
    int* jobs             = (int*)(ws + OFF_JOBS);
    int* njobs            = (int*)(ws + OFF_NJ);
    int* prog             = (int*)(ws + OFF_PROG);
    float* out            = (float*)d_out;

    prep_kernel<<<2405, 256, 0, stream>>>(x, W1, b1, W2, op_emb, tempers, ops,
                                          state, W1b, W2b, c1, counts, lists,
                                          jobs, njobs, prog);
    hops_kernel<<<256, 1024, 0, stream>>>(state, W1b, W2b, c1, b2,
                                          counts, lists, jobs, njobs, prog);
    final_kernel<<<128, 256, 0, stream>>>(state, ln_g, ln_b, Wt, bt, out);
}

// Round 7
// 140.851 us; speedup vs baseline: 1.3792x; 1.3792x over previous
//
#include <hip/hip_runtime.h>

typedef __attribute__((ext_vector_type(8))) short short8;
typedef __attribute__((ext_vector_type(4))) float floatx4;

// Problem constants
#define NEXP   36          // 12 tempers * 3 ops
#define NTOK   1024        // 128 batch * 8 patches
#define HOPS   4

// Workspace layout (bytes)
#define OFF_STATE   0u          // 1024*256*4      = 1,048,576
#define OFF_W1B     1048576u    // 36*65536*2      = 4,718,592 (bf16, swizzled)
#define OFF_W2B     5767168u    // 36*65536*2      = 4,718,592
#define OFF_C1      10485760u   // 36*256*4        = 36,864
#define OFF_COUNTS  10522624u   // 4*36*4          = 576
#define OFF_LISTS   10523264u   // 4*36*1024*4     = 589,824
#define OFF_JOBS    11113088u   // 4*128*4         = 2,048
#define OFF_NJ      11115136u   // 4*4             = 16   (end ~11.1 MB)

__device__ __forceinline__ unsigned short f2bf(float f) {
    unsigned u = __float_as_uint(f);
    u += 0x7FFFu + ((u >> 16) & 1u);   // round-to-nearest-even
    return (unsigned short)(u >> 16);
}

// ---------------------------------------------------------------------------
// PREP: one kernel, block-role partitioned. (x->state copy REMOVED: hop0
// reads x directly; final selects x vs state per token.)
//  blocks [0,2304)    : convert W1(first 256 rows)/W2 -> bf16 in B-frag layout
//                       Wb[e][kb][j][k32],  kb=k/32, k32=k%32
//  blocks [2304,2340) : c1[e][j] = b1[e][j] + sum_k emb[e][k]*W1[e][256+k][j]
//  block  2340        : routing + job compaction
// ---------------------------------------------------------------------------
__global__ __launch_bounds__(256) void prep_kernel(
    const float* __restrict__ W1, const float* __restrict__ b1,
    const float* __restrict__ W2, const float* __restrict__ op_emb,
    const int* __restrict__ tempers, const int* __restrict__ ops,
    unsigned short* __restrict__ W1b, unsigned short* __restrict__ W2b,
    float* __restrict__ c1, int* __restrict__ counts, int* __restrict__ lists,
    int* __restrict__ jobs, int* __restrict__ njobs)
{
    const int bid = blockIdx.x;
    const int t = threadIdx.x;

    if (bid < 2304) {
        // ---- weight convert + swizzle ----
        const int mat = bid / 1152;           // 0: W1, 1: W2
        const int id  = bid % 1152;           // 36 experts * 8 kb * 4 jt
        const int e   = id / 32;
        const int sub = id % 32;
        const int kb  = sub / 4;
        const int jt  = sub % 4;
        const float* src = mat ? (W2 + e * 65536) : (W1 + e * 98304);
        unsigned short* dst = (mat ? W2b : W1b) + e * 65536;
        const int j  = jt * 64 + (t & 63);
        const int ks = (t >> 6) * 8;          // 8 consecutive k per thread
        short8 v;
        #pragma unroll
        for (int i = 0; i < 8; i++)
            v[i] = (short)f2bf(src[(kb * 32 + ks + i) * 256 + j]);  // coalesced across j
        *(short8*)(dst + (kb * 256 + j) * 32 + ks) = v;
    } else if (bid < 2340) {
        // ---- c1 precompute (fp32) ----
        const int e = bid - 2304;
        __shared__ float eb[128];
        if (t < 128) eb[t] = op_emb[e * 128 + t];
        __syncthreads();
        float acc = b1[e * 256 + t];
        const float* wp = W1 + e * 98304 + 256 * 256;  // emb rows of W1[e]
        #pragma unroll 4
        for (int k = 0; k < 128; k++)
            acc += eb[k] * wp[k * 256 + t];
        c1[e * 256 + t] = acc;
    } else {
        // ---- routing (single block; cumulative-halt semantics) ----
        __shared__ int lc[HOPS * NEXP];
        if (t < HOPS * NEXP) lc[t] = 0;
        __syncthreads();
        for (int q = 0; q < 4; q++) {
            int n = q * 256 + t;
            bool act = true;
            for (int hop = 0; hop < HOPS; hop++) {
                int tt = tempers[hop * NTOK + n];
                int oo = ops[hop * NTOK + n];
                act = act && (tt != 12);       // 12 == halt; sticky
                if (act) {
                    int e = tt * 3 + oo;
                    int pos = atomicAdd(&lc[hop * NEXP + e], 1);
                    lists[(hop * NEXP + e) * NTOK + pos] = n;
                }
            }
        }
        __syncthreads();
        if (t < HOPS * NEXP) counts[t] = lc[t];
        // ---- job compaction: one thread per hop; job = (m0<<8)|e ----
        if (t < HOPS) {
            int hop = t, nj = 0;
            for (int e = 0; e < NEXP; e++) {
                int c = lc[hop * NEXP + e];
                for (int m0 = 0; m0 < c; m0 += 16)
                    jobs[hop * 128 + nj++] = (m0 << 8) | e;
            }
            njobs[hop] = nj;
        }
    }
}

// ---------------------------------------------------------------------------
// HOP: one job = (expert, 16-token tile), 1024 threads = 16 waves.
// __launch_bounds__(1024, 4): 4 waves/EU => 128-VGPR budget, so the 64-VGPR
// B-fragment preload STAYS IN REGISTERS (r6 profile showed VGPR_Count=60 with
// the default bounds — compiler sank B loads into the MFMA loop, serializing
// every MFMA on a ~500cy L2 load; that was the hidden per-hop cost).
// Wave w owns output columns [w*16,w*16+16).
//  GEMM1: h = relu(src_bf16 @ W1b + c1)   (c1 folds emb part + b1)
//  GEMM2: y = relu(h_bf16 @ W2b + b2)  -> state (f32)
// src = x for hop 0, state for hops 1..3 (sticky halt => rows valid).
// MFMA maps (m89): A[m=l&15][k=(l>>4)*8+i]; D col=l&15, row=(l>>4)*4+reg.
// ---------------------------------------------------------------------------
__global__ __launch_bounds__(1024, 4) void hop_kernel(
    const float* __restrict__ src, float* __restrict__ state,
    const unsigned short* __restrict__ W1b,
    const unsigned short* __restrict__ W2b,
    const float* __restrict__ c1, const float* __restrict__ b2,
    const int* __restrict__ counts, const int* __restrict__ lists,
    const int* __restrict__ jobs, const int* __restrict__ njobs, int hop)
{
    if (blockIdx.x >= njobs[hop]) return;  // uniform early-exit
    const int job = jobs[hop * 128 + blockIdx.x];
    const int e   = job & 0xFF;
    const int m0  = job >> 8;
    const int n_e = counts[hop * NEXP + e];
    const int mact = min(16, n_e - m0);

    const int t = threadIdx.x;
    const int l = t & 63, w = t >> 6;      // wave 0..15
    const int col = l & 15, g = l >> 4;
    const int j = w * 16 + col;            // this wave's output column

    // ---- preload B-frags for both GEMMs (kept register-resident) ----
    const unsigned short* Wp  = W1b + e * 65536;
    const unsigned short* Wp2 = W2b + e * 65536;
    short8 B1[8], B2[8];
    #pragma unroll
    for (int kb = 0; kb < 8; kb++) {
        B1[kb] = *(const short8*)(Wp  + (kb * 256 + j) * 32 + g * 8);
        B2[kb] = *(const short8*)(Wp2 + (kb * 256 + j) * 32 + g * 8);
    }
    const float cv = c1[e * 256 + j];
    const float bv = b2[e * 256 + j];

    __shared__ int toks[16];
    __shared__ unsigned short Ab[4096];    // [kb][lane][8] bf16, 8 KB
    __shared__ unsigned short Hb[4096];    // 8 KB

    if (t < 16) toks[t] = (t < mact) ? lists[(hop * NEXP + e) * NTOK + m0 + t] : 0;
    __syncthreads();

    // ---- stage A tile: src rows (f32) -> bf16 in A-frag layout ----
    {
        int m = t >> 6;                    // token row 0..15 (one wave per row)
        int k = (t & 63) * 4;              // float4 column
        float4 v = make_float4(0.f, 0.f, 0.f, 0.f);
        if (m < mact) v = *(const float4*)(src + toks[m] * 256 + k);
        int kb = k >> 5, gg = (k >> 3) & 3, i = k & 7;
        unsigned short* d = Ab + kb * 512 + (gg * 16 + m) * 8 + i;
        d[0] = f2bf(v.x); d[1] = f2bf(v.y); d[2] = f2bf(v.z); d[3] = f2bf(v.w);
    }
    __syncthreads();

    // ---- GEMM1 (weights in registers) ----
    floatx4 acc = (floatx4){cv, cv, cv, cv};
    #pragma unroll
    for (int kb = 0; kb < 8; kb++) {
        short8 a = *(const short8*)(Ab + kb * 512 + l * 8);
        acc = __builtin_amdgcn_mfma_f32_16x16x32_bf16(a, B1[kb], acc, 0, 0, 0);
    }
    // ---- epilogue 1: relu -> Hb in A-frag layout (h-dim becomes K) ----
    {
        int kb2 = j >> 5, g2 = (j >> 3) & 3, i2 = j & 7;
        #pragma unroll
        for (int r = 0; r < 4; r++) {
            int m = g * 4 + r;             // D row (token)
            float vv = acc[r];
            vv = vv > 0.f ? vv : 0.f;
            Hb[kb2 * 512 + (g2 * 16 + m) * 8 + i2] = f2bf(vv);
        }
    }
    __syncthreads();

    // ---- GEMM2 ----
    floatx4 acc2 = (floatx4){bv, bv, bv, bv};
    #pragma unroll
    for (int kb = 0; kb < 8; kb++) {
        short8 a = *(const short8*)(Hb + kb * 512 + l * 8);
        acc2 = __builtin_amdgcn_mfma_f32_16x16x32_bf16(a, B2[kb], acc2, 0, 0, 0);
    }
    // ---- epilogue 2: relu -> state (f32), only real rows ----
    #pragma unroll
    for (int r = 0; r < 4; r++) {
        int m = g * 4 + r;
        if (m < mact) {
            float vv = acc2[r];
            state[toks[m] * 256 + j] = vv > 0.f ? vv : 0.f;
        }
    }
}

// ---------------------------------------------------------------------------
// FINAL: mean-pool 8 patches -> LayerNorm -> 10-class head. One block/batch.
// Per-token source select: tokens halted at hop 0 (tempers[0][n]==12) were
// never written to state -> read x instead.
// ---------------------------------------------------------------------------
__global__ __launch_bounds__(256) void final_kernel(
    const float* __restrict__ x, const float* __restrict__ state,
    const int* __restrict__ tempers,
    const float* __restrict__ ln_g, const float* __restrict__ ln_b,
    const float* __restrict__ Wt, const float* __restrict__ bt,
    float* __restrict__ out)
{
    const int b = blockIdx.x, t = threadIdx.x;
    float s = 0.f;
    #pragma unroll
    for (int p = 0; p < 8; p++) {
        int n = b * 8 + p;
        const float* rowsrc = (tempers[n] != 12) ? state : x;
        s += rowsrc[n * 256 + t];
    }
    s *= 0.125f;

    float v1 = s, v2 = s * s;
    #pragma unroll
    for (int off = 32; off; off >>= 1) {
        v1 += __shfl_down(v1, off);
        v2 += __shfl_down(v2, off);
    }
    __shared__ float red[8];
    __shared__ float stats[2];
    const int w = t >> 6, l = t & 63;
    if (l == 0) { red[w] = v1; red[4 + w] = v2; }
    __syncthreads();
    if (t == 0) {
        float su = red[0] + red[1] + red[2] + red[3];
        float sq = red[4] + red[5] + red[6] + red[7];
        float mu = su * (1.0f / 256.0f);
        float var = sq * (1.0f / 256.0f) - mu * mu;
        stats[0] = mu;
        stats[1] = rsqrtf(var + 1e-5f);
    }
    __syncthreads();
    float normed = (s - stats[0]) * stats[1] * ln_g[t] + ln_b[t];

    __shared__ float pr[40];
    #pragma unroll
    for (int c = 0; c < 10; c++) {
        float pv = normed * Wt[t * 10 + c];
        #pragma unroll
        for (int off = 32; off; off >>= 1) pv += __shfl_down(pv, off);
        if (l == 0) pr[w * 10 + c] = pv;
    }
    __syncthreads();
    if (t < 10)
        out[b * 10 + t] = pr[t] + pr[10 + t] + pr[20 + t] + pr[30 + t] + bt[t];
}

extern "C" void kernel_launch(void* const* d_in, const int* in_sizes, int n_in,
                              void* d_out, int out_size, void* d_ws, size_t ws_size,
                              hipStream_t stream)
{
    const float* x      = (const float*)d_in[0];
    const float* W1     = (const float*)d_in[1];
    const float* b1     = (const float*)d_in[2];
    const float* W2     = (const float*)d_in[3];
    const float* b2     = (const float*)d_in[4];
    const float* op_emb = (const float*)d_in[5];
    const float* ln_g   = (const float*)d_in[6];
    const float* ln_b   = (const float*)d_in[7];
    const float* Wt     = (const float*)d_in[8];
    const float* bt     = (const float*)d_in[9];
    const int* tempers  = (const int*)d_in[10];
    const int* ops      = (const int*)d_in[11];

    char* ws = (char*)d_ws;
    float* state          = (float*)(ws + OFF_STATE);
    unsigned short* W1b   = (unsigned short*)(ws + OFF_W1B);
    unsigned short* W2b   = (unsigned short*)(ws + OFF_W2B);
    float* c1             = (float*)(ws + OFF_C1);
    int* counts           = (int*)(ws + OFF_COUNTS);
    int* lists            = (int*)(ws + OFF_LISTS);
    int* jobs             = (int*)(ws + OFF_JOBS);
    int* njobs            = (int*)(ws + OFF_NJ);
    float* out            = (float*)d_out;

    prep_kernel<<<2341, 256, 0, stream>>>(W1, b1, W2, op_emb, tempers, ops,
                                          W1b, W2b, c1, counts, lists,
                                          jobs, njobs);
    for (int hop = 0; hop < HOPS; hop++)
        hop_kernel<<<128, 1024, 0, stream>>>(hop == 0 ? x : state, state,
                                             W1b, W2b, c1, b2,
                                             counts, lists, jobs, njobs, hop);
    final_kernel<<<128, 256, 0, stream>>>(x, state, tempers,
                                          ln_g, ln_b, Wt, bt, out);
}